// Round 5
// baseline (75736.139 us; speedup 1.0000x reference)
//
#include <hip/hip_runtime.h>

#define TSTEPS 2048
#define NCHAIN 8
#define RDIM 1024
#define IDIM 128
#define HDIM 256
#define NB 16                    // blocks per chain
#define NTHR 576                 // 9 waves: 8 compute + 1 dedicated poller
#define NBLOCKS (NB * NCHAIN)    // 128 blocks: 1/CU, co-resident

typedef unsigned long long u64_t;

// Pin a float in a VGPR: defeat rematerialization of weight loads.
#define PIN(x) asm volatile("" : "+v"(x))

// Agent(device)-scope relaxed atomics: minimum scope for cross-block
// communication on gfx950 (per-XCD L2s not coherent; sc0 alone is
// shader-engine scope — insufficient for a 16-CU chain).
__device__ __forceinline__ u64_t aload64(const u64_t* p) {
  return __hip_atomic_load(p, __ATOMIC_RELAXED, __HIP_MEMORY_SCOPE_AGENT);
}
__device__ __forceinline__ void astore64(u64_t* p, u64_t v) {
  __hip_atomic_store(p, v, __ATOMIC_RELAXED, __HIP_MEMORY_SCOPE_AGENT);
}
// Tag-in-data: {float value (lo 32b), step tag (hi 32b)} in one atomic u64.
// Poison tag 0xAAAAAAAA never matches a wanted tag (wanted <= TSTEPS+1) ->
// no workspace memset needed.
__device__ __forceinline__ u64_t pack(float v, unsigned tag) {
  return ((u64_t)tag << 32) | (u64_t)__float_as_uint(v);
}
__device__ __forceinline__ float val_of(u64_t q) { return __uint_as_float((unsigned)q); }
__device__ __forceinline__ unsigned tag_of(u64_t q) { return (unsigned)(q >> 32); }

__device__ __forceinline__ float wave_sum(float v) {
  v += __shfl_xor(v, 1);
  v += __shfl_xor(v, 2);
  v += __shfl_xor(v, 4);
  v += __shfl_xor(v, 8);
  v += __shfl_xor(v, 16);
  v += __shfl_xor(v, 32);
  return v;
}

// R4 + ONE change: the pollers are a dedicated poll-only wave (wave 8).
// Waves 0-7: compute A/B/C exactly as R4. Wave 8: polls x_s + p_{s-1} +
// h_{s-2} starting IMMEDIATELY at step entry (overlapping the producers'
// compute), publishes to double-buffered LDS; one __syncthreads per step.
// R4's pollers (waves 0,1) polled only AFTER their own compute -> detection
// lagged store-visibility by 1-2 poll rounds; this removes that lag.
// Per-step skew (R0-identical): A: x_s; B: p_{s-1}; C: h_{s-2}.
// Ring safety: every cross-block load is tag-checked, so it COMPLETES before
// any later store of that wave issues; tag-chained induction certifies
// depth-2 x and depth-4 p/h rings (validated by R1/R3/R4 passing).
__global__ __launch_bounds__(NTHR, 1) void esn_fused(
    const float* __restrict__ u, const float* __restrict__ w_in,
    const float* __restrict__ w, const float* __restrict__ w_bias,
    const float* __restrict__ w_pca, const float* __restrict__ wzp,
    const float* __restrict__ wzh, const float* __restrict__ bz,
    float* __restrict__ out,
    u64_t* __restrict__ x_buf,   // [2][8][1024] tagged
    u64_t* __restrict__ p_buf,   // [4][8][256] tagged
    u64_t* __restrict__ h_buf)   // [4][8][256] tagged
{
  const int bid = blockIdx.x;
  const int chain = bid & 7;           // round-robin -> same-XCD locality
  const int sub = bid >> 3;            // 0..15
  const int tid = threadIdx.x;
  const int wave = tid >> 6;           // 0..8
  const int lane = tid & 63;
  const int wv = wave & 7;             // weight addressing: wave 8 duplicates
                                       // wave 0 (valid addrs, never used)
  const bool is_compute = (wave < 8);

  // double-buffered broadcast staging (12 KB)
  __shared__ float lds_x[2][RDIM];
  __shared__ float lds_p[2][HDIM];
  __shared__ float lds_h[2][HDIM];

  // ---- phase-A weights: 8 rows of W per wave; lane owns cols [lane*16,+16) ----
  const int rrow0 = sub * 64 + wv * 8;
  float4 WA[8][4];
  #pragma unroll
  for (int j = 0; j < 8; ++j)
    #pragma unroll
    for (int i = 0; i < 4; ++i)
      WA[j][i] = *reinterpret_cast<const float4*>(
          w + (size_t)(rrow0 + j) * RDIM + lane * 16 + i * 4);
  float2 Wi[8];
  #pragma unroll
  for (int j = 0; j < 8; ++j)
    Wi[j] = *reinterpret_cast<const float2*>(w_in + (size_t)(rrow0 + j) * IDIM + lane * 2);
  float wb = (lane < 8) ? w_bias[rrow0 + lane] : 0.f;

  // ---- phase-B weights: 2 cols of w_pca per wave ----
  const int pcol0 = sub * 16 + wv * 2;
  float Wp[2][16];
  #pragma unroll
  for (int j = 0; j < 2; ++j)
    #pragma unroll
    for (int k = 0; k < 16; ++k)
      Wp[j][k] = w_pca[(size_t)(lane * 16 + k) * HDIM + pcol0 + j];

  // ---- phase-C weights: 2 rows of wzp/wzh per wave ----
  const int grow0 = sub * 16 + wv * 2;
  float4 Zp[2], Zh[2];
  #pragma unroll
  for (int j = 0; j < 2; ++j) {
    Zp[j] = *reinterpret_cast<const float4*>(wzp + (size_t)(grow0 + j) * HDIM + lane * 4);
    Zh[j] = *reinterpret_cast<const float4*>(wzh + (size_t)(grow0 + j) * HDIM + lane * 4);
  }
  float bzr = (lane < 2) ? bz[grow0 + lane] : 0.f;

  // ---- pin all weights into live VGPRs ----
  #pragma unroll
  for (int j = 0; j < 8; ++j)
    #pragma unroll
    for (int i = 0; i < 4; ++i) {
      PIN(WA[j][i].x); PIN(WA[j][i].y); PIN(WA[j][i].z); PIN(WA[j][i].w);
    }
  #pragma unroll
  for (int j = 0; j < 8; ++j) { PIN(Wi[j].x); PIN(Wi[j].y); }
  #pragma unroll
  for (int j = 0; j < 2; ++j)
    #pragma unroll
    for (int k = 0; k < 16; ++k) PIN(Wp[j][k]);
  #pragma unroll
  for (int j = 0; j < 2; ++j) {
    PIN(Zp[j].x); PIN(Zp[j].y); PIN(Zp[j].z); PIN(Zp[j].w);
    PIN(Zh[j].x); PIN(Zh[j].y); PIN(Zh[j].z); PIN(Zh[j].w);
  }
  PIN(wb); PIN(bzr);

  for (int s = 0; s < TSTEPS + 2; ++s) {
    const int cur = s & 1;               // LDS buffer filled during step s-1
    const int nxt = (s + 1) & 1;

    if (is_compute) {
      // ---- x_{s-1} from LDS (published by poller during step s-1) ----
      float xc[16];
      const bool xc_valid = (s >= 1 && s <= TSTEPS);
      if (xc_valid) {
        #pragma unroll
        for (int k = 0; k < 16; ++k) xc[k] = lds_x[cur][k * 64 + lane];
      }

      // ---------------- phase A: x_s ----------------
      if (s < TSTEPS) {
        float acc[8];
        float2 uu = *reinterpret_cast<const float2*>(
            u + ((size_t)chain * TSTEPS + s) * IDIM + lane * 2);
        #pragma unroll
        for (int j = 0; j < 8; ++j) acc[j] = Wi[j].x * uu.x + Wi[j].y * uu.y;
        if (s > 0) {
          #pragma unroll
          for (int j = 0; j < 8; ++j) {
            float a = acc[j];
            #pragma unroll
            for (int i = 0; i < 4; ++i) {
              a += WA[j][i].x * xc[i * 4 + 0];
              a += WA[j][i].y * xc[i * 4 + 1];
              a += WA[j][i].z * xc[i * 4 + 2];
              a += WA[j][i].w * xc[i * 4 + 3];
            }
            acc[j] = a;
          }
        }
        #pragma unroll
        for (int j = 0; j < 8; ++j) acc[j] = wave_sum(acc[j]);
        float v = acc[0];
        #pragma unroll
        for (int j = 1; j < 8; ++j) v = (lane == j) ? acc[j] : v;
        if (lane < 8)
          astore64(x_buf + (((s & 1) * NCHAIN) + chain) * RDIM + rrow0 + lane,
                   pack(tanhf(v + wb), (unsigned)(s + 1)));
      }

      // ---------------- phase B: p_{s-1} (reuses xc) ----------------
      if (xc_valid) {
        const int t = s - 1;
        float a0 = 0.f, a1 = 0.f;
        #pragma unroll
        for (int k = 0; k < 16; ++k) { a0 += Wp[0][k] * xc[k]; a1 += Wp[1][k] * xc[k]; }
        a0 = wave_sum(a0);
        a1 = wave_sum(a1);
        float v = (lane == 1) ? a1 : a0;
        if (lane < 2)
          astore64(p_buf + (((t & 3) * NCHAIN) + chain) * HDIM + pcol0 + lane,
                   pack(v, (unsigned)(t + 1)));
      }

      // ---------------- phase C: h_{s-2} (LDS-fed) ----------------
      if (s >= 2) {
        const int t = s - 2;
        float pc[4], hc[4];
        #pragma unroll
        for (int k = 0; k < 4; ++k) pc[k] = lds_p[cur][k * 64 + lane];
        if (t > 0) {
          #pragma unroll
          for (int k = 0; k < 4; ++k) hc[k] = lds_h[cur][k * 64 + lane];
        } else {
          hc[0] = hc[1] = hc[2] = hc[3] = 0.f;
        }
        float a0 = Zp[0].x * pc[0] + Zp[0].y * pc[1] + Zp[0].z * pc[2] + Zp[0].w * pc[3]
                 + Zh[0].x * hc[0] + Zh[0].y * hc[1] + Zh[0].z * hc[2] + Zh[0].w * hc[3];
        float a1 = Zp[1].x * pc[0] + Zp[1].y * pc[1] + Zp[1].z * pc[2] + Zp[1].w * pc[3]
                 + Zh[1].x * hc[0] + Zh[1].y * hc[1] + Zh[1].z * hc[2] + Zh[1].w * hc[3];
        a0 = wave_sum(a0);
        a1 = wave_sum(a1);
        float v = (lane == 1) ? a1 : a0;
        if (lane < 2) {
          const int row = grow0 + lane;
          float z = 1.f / (1.f + expf(-(v + bzr)));
          float pt = lds_p[cur][(row & 3) * 64 + (row >> 2)];
          float hp = (t > 0) ? lds_h[cur][(row & 3) * 64 + (row >> 2)] : 0.f;
          float hnew = hp + z * (pt - hp);
          astore64(h_buf + (((t & 3) * NCHAIN) + chain) * HDIM + row,
                   pack(hnew, (unsigned)(t + 1)));
          out[((size_t)chain * TSTEPS + t) * HDIM + row] = hnew;  // fp32 output
        }
      }
    } else {
      // ---- dedicated poller (wave 8): fetch step-(s+1) data, publish ----
      // Runs concurrently with the compute waves' A/B/C above: polling
      // starts at step entry, so detection ~coincides with visibility.
      const bool needx = (s <= TSTEPS - 1);         // x_s, tag s+1
      const bool needp = (s >= 1 && s <= TSTEPS);   // p_{s-1}, tag s
      const bool needh = (s >= 2 && s <= TSTEPS);   // h_{s-2}, tag s-1
      if (needx || needp) {
        const u64_t* xp =
            x_buf + (((s & 1) * NCHAIN) + chain) * RDIM + lane * 16;
        const u64_t* pvp =
            p_buf + ((((s - 1) & 3) * NCHAIN) + chain) * HDIM + lane * 4;
        const u64_t* hvp =
            h_buf + ((((s - 2) & 3) * NCHAIN) + chain) * HDIM + lane * 4;
        const unsigned wantx = (unsigned)(s + 1);
        const unsigned wantp = (unsigned)s;
        const unsigned wanth = (unsigned)(s - 1);
        u64_t qx[16], qp[4], qh[4];
        unsigned it = 0;
        for (;;) {
          bool ok = true;
          if (needx) {
            #pragma unroll
            for (int k = 0; k < 16; ++k) qx[k] = aload64(xp + k);
          }
          if (needp) {
            #pragma unroll
            for (int k = 0; k < 4; ++k) qp[k] = aload64(pvp + k);
          }
          if (needh) {
            #pragma unroll
            for (int k = 0; k < 4; ++k) qh[k] = aload64(hvp + k);
          }
          if (needx) {
            #pragma unroll
            for (int k = 0; k < 16; ++k) ok = ok & (tag_of(qx[k]) == wantx);
          }
          if (needp) {
            #pragma unroll
            for (int k = 0; k < 4; ++k) ok = ok & (tag_of(qp[k]) == wantp);
          }
          if (needh) {
            #pragma unroll
            for (int k = 0; k < 4; ++k) ok = ok & (tag_of(qh[k]) == wanth);
          }
          if (ok) break;
          __builtin_amdgcn_s_sleep(1);
          if (++it > (1u << 17)) break;  // watchdog: wrong > hung
        }
        if (needx) {
          #pragma unroll
          for (int k = 0; k < 16; ++k) lds_x[nxt][k * 64 + lane] = val_of(qx[k]);
        }
        if (needp) {
          #pragma unroll
          for (int k = 0; k < 4; ++k) lds_p[nxt][k * 64 + lane] = val_of(qp[k]);
        }
        if (needh) {
          #pragma unroll
          for (int k = 0; k < 4; ++k) lds_h[nxt][k * 64 + lane] = val_of(qh[k]);
        }
      }
    }
    __syncthreads();
  }
}

extern "C" void kernel_launch(void* const* d_in, const int* in_sizes, int n_in,
                              void* d_out, int out_size, void* d_ws, size_t ws_size,
                              hipStream_t stream) {
  // Size-based remap (defensive); positional fallback. All fp32.
  const float* ptrs[8] = {nullptr};
  const int want[8] = {TSTEPS * NCHAIN * IDIM, RDIM * IDIM, RDIM * RDIM, RDIM,
                       RDIM * HDIM, HDIM * HDIM, HDIM * HDIM, HDIM};
  if (n_in == 8) {
    int used[8] = {0};
    for (int k = 0; k < 8; ++k)
      for (int i = 0; i < n_in; ++i)
        if (!used[i] && in_sizes[i] == want[k]) {
          ptrs[k] = (const float*)d_in[i]; used[i] = 1; break;
        }
  }
  bool ok = true;
  for (int k = 0; k < 8; ++k) ok = ok && (ptrs[k] != nullptr);
  if (!ok)
    for (int k = 0; k < 8; ++k) ptrs[k] = (const float*)d_in[k];

  float* out = (float*)d_out;  // reference output dtype: float32

  // workspace: tagged u64 rings. Harness re-poisons 0xAA before every launch;
  // poison tags never match a wanted tag, so NO memset is needed.
  u64_t* x_buf = (u64_t*)d_ws;                       // 2*8*1024  (128 KB)
  u64_t* p_buf = x_buf + 2 * NCHAIN * RDIM;          // 4*8*256   (64 KB)
  u64_t* h_buf = p_buf + 4 * NCHAIN * HDIM;          // 4*8*256   (64 KB)
  size_t need_u64 = (size_t)(2 * NCHAIN * RDIM + 2 * 4 * NCHAIN * HDIM);
  if (ws_size < need_u64 * 8) return;  // zero-output diagnostic signature

  esn_fused<<<dim3(NBLOCKS), dim3(NTHR), 0, stream>>>(
      ptrs[0], ptrs[1], ptrs[2], ptrs[3], ptrs[4], ptrs[5], ptrs[6], ptrs[7],
      out, x_buf, p_buf, h_buf);
}

// Round 6
// 21768.599 us; speedup vs baseline: 3.4791x; 3.4791x over previous
//
#include <hip/hip_runtime.h>

#define TSTEPS 2048
#define NCHAIN 8
#define RDIM 1024
#define IDIM 128
#define HDIM 256
#define KFOLD 2                   // chains folded per 16-block set
#define NSETS (NCHAIN / KFOLD)    // 4 sets
#define NB 16                     // blocks per set
#define NTHR 512                  // 8 waves — at the 2-waves/SIMD register
                                  // cliff; R5 proved 9 waves => spill => 6x
#define NBLOCKS (NB * NSETS)      // 64 blocks

typedef unsigned long long u64_t;

// Pin a float in a VGPR: defeat rematerialization of weight loads.
#define PIN(x) asm volatile("" : "+v"(x))

// Agent(device)-scope relaxed atomics: minimum scope for cross-block
// communication on gfx950 (per-XCD L2s not coherent; sc0 is SE-scope).
__device__ __forceinline__ u64_t aload64(const u64_t* p) {
  return __hip_atomic_load(p, __ATOMIC_RELAXED, __HIP_MEMORY_SCOPE_AGENT);
}
__device__ __forceinline__ void astore64(u64_t* p, u64_t v) {
  __hip_atomic_store(p, v, __ATOMIC_RELAXED, __HIP_MEMORY_SCOPE_AGENT);
}
// Tag-in-data: {float value (lo 32b), step tag (hi 32b)} in one atomic u64.
// Poison tag 0xAAAAAAAA never matches a wanted tag -> no memset needed.
__device__ __forceinline__ u64_t pack(float v, unsigned tag) {
  return ((u64_t)tag << 32) | (u64_t)__float_as_uint(v);
}
__device__ __forceinline__ float val_of(u64_t q) { return __uint_as_float((unsigned)q); }
__device__ __forceinline__ unsigned tag_of(u64_t q) { return (unsigned)(q >> 32); }

__device__ __forceinline__ float wave_sum(float v) {
  v += __shfl_xor(v, 1);
  v += __shfl_xor(v, 2);
  v += __shfl_xor(v, 4);
  v += __shfl_xor(v, 8);
  v += __shfl_xor(v, 16);
  v += __shfl_xor(v, 32);
  return v;
}

// R4 mechanism (dedicated pollers waves 0/1 + LDS broadcast, 8 waves) +
// KFOLD=2 chain folding. Weights are batch-shared: one 16-block set serves
// 2 chains round-robin with the SAME pinned weight registers.
// Slot j: compute chain c=set*2+(j&1), step s=j>>1 (phases A/B/C identical
// to R0/R4). Pollers fetch data for slot j+1, which was PRODUCED in slot
// j-1 -> one full slot (~1.5us) of production slack -> first-round poll
// hits. Reader count stays 2 waves/block (R3's failure was folding with
// 8 polling waves/block saturating the MALL request path).
// Ring safety: tag-checked loads complete before the block's barrier; later
// stores issue after it; cross-block induction through the tag chain
// certifies depth-2 x and depth-4 p/h rings (R1/R3/R4-validated).
__global__ __launch_bounds__(NTHR, 1) void esn_fused(
    const float* __restrict__ u, const float* __restrict__ w_in,
    const float* __restrict__ w, const float* __restrict__ w_bias,
    const float* __restrict__ w_pca, const float* __restrict__ wzp,
    const float* __restrict__ wzh, const float* __restrict__ bz,
    float* __restrict__ out,
    u64_t* __restrict__ x_buf,   // [2][8][1024] tagged
    u64_t* __restrict__ p_buf,   // [4][8][256] tagged
    u64_t* __restrict__ h_buf)   // [4][8][256] tagged
{
  const int bid = blockIdx.x;
  const int sub = bid & (NB - 1);      // 0..15 (position within set)
  const int set = bid >> 4;            // 0..3  (which chain pair)
  const int tid = threadIdx.x;
  const int wave = tid >> 6;           // 0..7
  const int lane = tid & 63;

  // double-buffered broadcast staging (12 KB), indexed by slot parity:
  // consumers read buf[j&1]; pollers during slot j write buf[(j+1)&1]
  __shared__ float lds_x[2][RDIM];
  __shared__ float lds_p[2][HDIM];
  __shared__ float lds_h[2][HDIM];

  // ---- phase-A weights: 8 rows of W per wave; lane owns cols [lane*16,+16) ----
  const int rrow0 = sub * 64 + wave * 8;
  float4 WA[8][4];
  #pragma unroll
  for (int j = 0; j < 8; ++j)
    #pragma unroll
    for (int i = 0; i < 4; ++i)
      WA[j][i] = *reinterpret_cast<const float4*>(
          w + (size_t)(rrow0 + j) * RDIM + lane * 16 + i * 4);
  float2 Wi[8];
  #pragma unroll
  for (int j = 0; j < 8; ++j)
    Wi[j] = *reinterpret_cast<const float2*>(w_in + (size_t)(rrow0 + j) * IDIM + lane * 2);
  float wb = (lane < 8) ? w_bias[rrow0 + lane] : 0.f;

  // ---- phase-B weights: 2 cols of w_pca per wave ----
  const int pcol0 = sub * 16 + wave * 2;
  float Wp[2][16];
  #pragma unroll
  for (int j = 0; j < 2; ++j)
    #pragma unroll
    for (int k = 0; k < 16; ++k)
      Wp[j][k] = w_pca[(size_t)(lane * 16 + k) * HDIM + pcol0 + j];

  // ---- phase-C weights: 2 rows of wzp/wzh per wave ----
  const int grow0 = sub * 16 + wave * 2;
  float4 Zp[2], Zh[2];
  #pragma unroll
  for (int j = 0; j < 2; ++j) {
    Zp[j] = *reinterpret_cast<const float4*>(wzp + (size_t)(grow0 + j) * HDIM + lane * 4);
    Zh[j] = *reinterpret_cast<const float4*>(wzh + (size_t)(grow0 + j) * HDIM + lane * 4);
  }
  float bzr = (lane < 2) ? bz[grow0 + lane] : 0.f;

  // ---- pin all weights into live VGPRs ----
  #pragma unroll
  for (int j = 0; j < 8; ++j)
    #pragma unroll
    for (int i = 0; i < 4; ++i) {
      PIN(WA[j][i].x); PIN(WA[j][i].y); PIN(WA[j][i].z); PIN(WA[j][i].w);
    }
  #pragma unroll
  for (int j = 0; j < 8; ++j) { PIN(Wi[j].x); PIN(Wi[j].y); }
  #pragma unroll
  for (int j = 0; j < 2; ++j)
    #pragma unroll
    for (int k = 0; k < 16; ++k) PIN(Wp[j][k]);
  #pragma unroll
  for (int j = 0; j < 2; ++j) {
    PIN(Zp[j].x); PIN(Zp[j].y); PIN(Zp[j].z); PIN(Zp[j].w);
    PIN(Zh[j].x); PIN(Zh[j].y); PIN(Zh[j].z); PIN(Zh[j].w);
  }
  PIN(wb); PIN(bzr);

  const int NSLOT = KFOLD * (TSTEPS + 2);    // 4100
  for (int slot = 0; slot < NSLOT; ++slot) {
    const int ci = slot & 1;
    const int chain = set * KFOLD + ci;
    const int s = slot >> 1;             // this slot's per-chain step
    const int cur = slot & 1;            // LDS buffer filled during slot-1
    const int nxt = (slot + 1) & 1;

    // ---- x_{s-1} from LDS (published by pollers during slot-1) ----
    float xc[16];
    const bool xc_valid = (s >= 1 && s <= TSTEPS);
    if (xc_valid) {
      #pragma unroll
      for (int k = 0; k < 16; ++k) xc[k] = lds_x[cur][k * 64 + lane];
    }

    // ---------------- phase A: x_s ----------------
    if (s < TSTEPS) {
      float acc[8];
      float2 uu = *reinterpret_cast<const float2*>(
          u + ((size_t)chain * TSTEPS + s) * IDIM + lane * 2);
      #pragma unroll
      for (int j = 0; j < 8; ++j) acc[j] = Wi[j].x * uu.x + Wi[j].y * uu.y;
      if (s > 0) {
        #pragma unroll
        for (int j = 0; j < 8; ++j) {
          float a = acc[j];
          #pragma unroll
          for (int i = 0; i < 4; ++i) {
            a += WA[j][i].x * xc[i * 4 + 0];
            a += WA[j][i].y * xc[i * 4 + 1];
            a += WA[j][i].z * xc[i * 4 + 2];
            a += WA[j][i].w * xc[i * 4 + 3];
          }
          acc[j] = a;
        }
      }
      #pragma unroll
      for (int j = 0; j < 8; ++j) acc[j] = wave_sum(acc[j]);
      float v = acc[0];
      #pragma unroll
      for (int j = 1; j < 8; ++j) v = (lane == j) ? acc[j] : v;
      if (lane < 8)
        astore64(x_buf + (((s & 1) * NCHAIN) + chain) * RDIM + rrow0 + lane,
                 pack(tanhf(v + wb), (unsigned)(s + 1)));
    }

    // ---------------- phase B: p_{s-1} (reuses xc) ----------------
    if (xc_valid) {
      const int t = s - 1;
      float a0 = 0.f, a1 = 0.f;
      #pragma unroll
      for (int k = 0; k < 16; ++k) { a0 += Wp[0][k] * xc[k]; a1 += Wp[1][k] * xc[k]; }
      a0 = wave_sum(a0);
      a1 = wave_sum(a1);
      float v = (lane == 1) ? a1 : a0;
      if (lane < 2)
        astore64(p_buf + (((t & 3) * NCHAIN) + chain) * HDIM + pcol0 + lane,
                 pack(v, (unsigned)(t + 1)));
    }

    // ---------------- phase C: h_{s-2} (LDS-fed) ----------------
    if (s >= 2) {
      const int t = s - 2;
      float pc[4], hc[4];
      #pragma unroll
      for (int k = 0; k < 4; ++k) pc[k] = lds_p[cur][k * 64 + lane];
      if (t > 0) {
        #pragma unroll
        for (int k = 0; k < 4; ++k) hc[k] = lds_h[cur][k * 64 + lane];
      } else {
        hc[0] = hc[1] = hc[2] = hc[3] = 0.f;
      }
      float a0 = Zp[0].x * pc[0] + Zp[0].y * pc[1] + Zp[0].z * pc[2] + Zp[0].w * pc[3]
               + Zh[0].x * hc[0] + Zh[0].y * hc[1] + Zh[0].z * hc[2] + Zh[0].w * hc[3];
      float a1 = Zp[1].x * pc[0] + Zp[1].y * pc[1] + Zp[1].z * pc[2] + Zp[1].w * pc[3]
               + Zh[1].x * hc[0] + Zh[1].y * hc[1] + Zh[1].z * hc[2] + Zh[1].w * hc[3];
      a0 = wave_sum(a0);
      a1 = wave_sum(a1);
      float v = (lane == 1) ? a1 : a0;
      if (lane < 2) {
        const int row = grow0 + lane;
        float z = 1.f / (1.f + expf(-(v + bzr)));
        float pt = lds_p[cur][(row & 3) * 64 + (row >> 2)];
        float hp = (t > 0) ? lds_h[cur][(row & 3) * 64 + (row >> 2)] : 0.f;
        float hnew = hp + z * (pt - hp);
        astore64(h_buf + (((t & 3) * NCHAIN) + chain) * HDIM + row,
                 pack(hnew, (unsigned)(t + 1)));
        out[((size_t)chain * TSTEPS + t) * HDIM + row] = hnew;  // fp32 output
      }
    }

    // ---- pollers (waves 0,1): fetch slot-(j+1) consumer data ----
    // Consumer slot j+1 = chain c1, step s1. Items were produced in slot
    // j-1 (one slot of visibility slack -> first-round hits expected).
    {
      const int c1 = set * KFOLD + ((slot + 1) & 1);
      const int s1 = (slot + 1) >> 1;
      if (wave == 0) {
        const bool needx = (s1 >= 1 && s1 <= TSTEPS);   // x_{s1-1}, tag s1
        if (needx) {
          const u64_t* xp =
              x_buf + ((((s1 - 1) & 1) * NCHAIN) + c1) * RDIM + lane * 16;
          const unsigned want = (unsigned)s1;
          u64_t q[16];
          unsigned it = 0;
          for (;;) {
            bool ok = true;
            #pragma unroll
            for (int k = 0; k < 16; ++k) q[k] = aload64(xp + k);
            #pragma unroll
            for (int k = 0; k < 16; ++k) ok = ok & (tag_of(q[k]) == want);
            if (ok) break;
            __builtin_amdgcn_s_sleep(1);
            if (++it > (1u << 17)) break;  // watchdog: wrong > hung
          }
          #pragma unroll
          for (int k = 0; k < 16; ++k) lds_x[nxt][k * 64 + lane] = val_of(q[k]);
        }
      } else if (wave == 1) {
        const bool needp = (s1 >= 2 && s1 <= TSTEPS + 1);  // p_{s1-2}, tag s1-1
        const bool needh = (s1 >= 3 && s1 <= TSTEPS + 1);  // h_{s1-3}, tag s1-2
        if (needp) {
          const u64_t* pvp =
              p_buf + ((((s1 - 2) & 3) * NCHAIN) + c1) * HDIM + lane * 4;
          const u64_t* hvp =
              h_buf + ((((s1 - 3) & 3) * NCHAIN) + c1) * HDIM + lane * 4;
          const unsigned wantp = (unsigned)(s1 - 1);
          const unsigned wanth = (unsigned)(s1 - 2);
          u64_t qp[4], qh[4];
          unsigned it = 0;
          for (;;) {
            bool ok = true;
            #pragma unroll
            for (int k = 0; k < 4; ++k) qp[k] = aload64(pvp + k);
            if (needh) {
              #pragma unroll
              for (int k = 0; k < 4; ++k) qh[k] = aload64(hvp + k);
            }
            #pragma unroll
            for (int k = 0; k < 4; ++k) ok = ok & (tag_of(qp[k]) == wantp);
            if (needh) {
              #pragma unroll
              for (int k = 0; k < 4; ++k) ok = ok & (tag_of(qh[k]) == wanth);
            }
            if (ok) break;
            __builtin_amdgcn_s_sleep(1);
            if (++it > (1u << 17)) break;
          }
          #pragma unroll
          for (int k = 0; k < 4; ++k) lds_p[nxt][k * 64 + lane] = val_of(qp[k]);
          if (needh) {
            #pragma unroll
            for (int k = 0; k < 4; ++k) lds_h[nxt][k * 64 + lane] = val_of(qh[k]);
          }
        }
      }
    }
    __syncthreads();
  }
}

extern "C" void kernel_launch(void* const* d_in, const int* in_sizes, int n_in,
                              void* d_out, int out_size, void* d_ws, size_t ws_size,
                              hipStream_t stream) {
  // Size-based remap (defensive); positional fallback. All fp32.
  const float* ptrs[8] = {nullptr};
  const int want[8] = {TSTEPS * NCHAIN * IDIM, RDIM * IDIM, RDIM * RDIM, RDIM,
                       RDIM * HDIM, HDIM * HDIM, HDIM * HDIM, HDIM};
  if (n_in == 8) {
    int used[8] = {0};
    for (int k = 0; k < 8; ++k)
      for (int i = 0; i < n_in; ++i)
        if (!used[i] && in_sizes[i] == want[k]) {
          ptrs[k] = (const float*)d_in[i]; used[i] = 1; break;
        }
  }
  bool ok = true;
  for (int k = 0; k < 8; ++k) ok = ok && (ptrs[k] != nullptr);
  if (!ok)
    for (int k = 0; k < 8; ++k) ptrs[k] = (const float*)d_in[k];

  float* out = (float*)d_out;  // reference output dtype: float32

  // workspace: tagged u64 rings. Harness re-poisons 0xAA before every launch;
  // poison tags never match a wanted tag, so NO memset is needed.
  u64_t* x_buf = (u64_t*)d_ws;                       // 2*8*1024  (128 KB)
  u64_t* p_buf = x_buf + 2 * NCHAIN * RDIM;          // 4*8*256   (64 KB)
  u64_t* h_buf = p_buf + 4 * NCHAIN * HDIM;          // 4*8*256   (64 KB)
  size_t need_u64 = (size_t)(2 * NCHAIN * RDIM + 2 * 4 * NCHAIN * HDIM);
  if (ws_size < need_u64 * 8) return;  // zero-output diagnostic signature

  esn_fused<<<dim3(NBLOCKS), dim3(NTHR), 0, stream>>>(
      ptrs[0], ptrs[1], ptrs[2], ptrs[3], ptrs[4], ptrs[5], ptrs[6], ptrs[7],
      out, x_buf, p_buf, h_buf);
}

// Round 7
// 14858.858 us; speedup vs baseline: 5.0970x; 1.4650x over previous
//
#include <hip/hip_runtime.h>

#define TSTEPS 2048
#define NCHAIN 8
#define RDIM 1024
#define IDIM 128
#define HDIM 256
#define NB 16                    // blocks per chain
#define NTHR 512                 // 8 waves — at the 2-waves/SIMD register
                                 // cliff; R5 proved 9 waves => spill => 6x
#define NBLOCKS (NB * NCHAIN)    // 128 blocks: 1/CU, co-resident

typedef unsigned long long u64_t;

// Pin a float in a VGPR: defeat rematerialization of weight loads.
#define PIN(x) asm volatile("" : "+v"(x))

// Agent(device)-scope relaxed atomics: minimum scope for cross-block
// communication on gfx950 (per-XCD L2s not coherent; sc0 is SE-scope).
__device__ __forceinline__ u64_t aload64(const u64_t* p) {
  return __hip_atomic_load(p, __ATOMIC_RELAXED, __HIP_MEMORY_SCOPE_AGENT);
}
__device__ __forceinline__ void astore64(u64_t* p, u64_t v) {
  __hip_atomic_store(p, v, __ATOMIC_RELAXED, __HIP_MEMORY_SCOPE_AGENT);
}
// Tag-in-data: {float value (lo 32b), step tag (hi 32b)} in one atomic u64.
// Poison tag 0xAAAAAAAA never matches a wanted tag -> no memset needed.
__device__ __forceinline__ u64_t pack(float v, unsigned tag) {
  return ((u64_t)tag << 32) | (u64_t)__float_as_uint(v);
}
__device__ __forceinline__ float val_of(u64_t q) { return __uint_as_float((unsigned)q); }
__device__ __forceinline__ unsigned tag_of(u64_t q) { return (unsigned)(q >> 32); }

__device__ __forceinline__ float wave_sum(float v) {
  v += __shfl_xor(v, 1);
  v += __shfl_xor(v, 2);
  v += __shfl_xor(v, 4);
  v += __shfl_xor(v, 8);
  v += __shfl_xor(v, 16);
  v += __shfl_xor(v, 32);
  return v;
}

// R4 + ONE change: poll loads batched in inline asm.
// DIAGNOSIS (R0/R4/R6): every mechanism converged on ~5.3-5.8us per
// exchange cycle == 16 x ~0.33us — the HIP atomic-load path serializes the
// poll's 16 loads (per-load waits), so each round pays 16 MALL round-trips.
// FIX: issue 16 (resp. 8) global_load_dwordx2 sc1 back-to-back with ONE
// s_waitcnt vmcnt(0), then tag-check. Semantics identical to aload64
// (device-scope relaxed, L1-bypass via sc1); one pipelined round ~0.4us.
// Everything else is byte-identical to R4 (passed, 11784us):
//   waves 0/1 compute A/B/C then poll next-step data, publish to
//   double-buffered LDS; one __syncthreads per step.
// Ring safety: tag-checked loads complete (vmcnt0 in-asm) before the
// barrier and before any later store issues; tag-chained induction
// certifies depth-2 x / depth-4 p/h rings (R1/R3/R4/R6-validated).
__global__ __launch_bounds__(NTHR, 1) void esn_fused(
    const float* __restrict__ u, const float* __restrict__ w_in,
    const float* __restrict__ w, const float* __restrict__ w_bias,
    const float* __restrict__ w_pca, const float* __restrict__ wzp,
    const float* __restrict__ wzh, const float* __restrict__ bz,
    float* __restrict__ out,
    u64_t* __restrict__ x_buf,   // [2][8][1024] tagged
    u64_t* __restrict__ p_buf,   // [4][8][256] tagged
    u64_t* __restrict__ h_buf)   // [4][8][256] tagged
{
  const int bid = blockIdx.x;
  const int chain = bid & 7;           // round-robin -> same-XCD locality
  const int sub = bid >> 3;            // 0..15
  const int tid = threadIdx.x;
  const int wave = tid >> 6;           // 0..7
  const int lane = tid & 63;

  // double-buffered broadcast staging (12 KB)
  __shared__ float lds_x[2][RDIM];
  __shared__ float lds_p[2][HDIM];
  __shared__ float lds_h[2][HDIM];

  // ---- phase-A weights: 8 rows of W per wave; lane owns cols [lane*16,+16) ----
  const int rrow0 = sub * 64 + wave * 8;
  float4 WA[8][4];
  #pragma unroll
  for (int j = 0; j < 8; ++j)
    #pragma unroll
    for (int i = 0; i < 4; ++i)
      WA[j][i] = *reinterpret_cast<const float4*>(
          w + (size_t)(rrow0 + j) * RDIM + lane * 16 + i * 4);
  float2 Wi[8];
  #pragma unroll
  for (int j = 0; j < 8; ++j)
    Wi[j] = *reinterpret_cast<const float2*>(w_in + (size_t)(rrow0 + j) * IDIM + lane * 2);
  float wb = (lane < 8) ? w_bias[rrow0 + lane] : 0.f;

  // ---- phase-B weights: 2 cols of w_pca per wave ----
  const int pcol0 = sub * 16 + wave * 2;
  float Wp[2][16];
  #pragma unroll
  for (int j = 0; j < 2; ++j)
    #pragma unroll
    for (int k = 0; k < 16; ++k)
      Wp[j][k] = w_pca[(size_t)(lane * 16 + k) * HDIM + pcol0 + j];

  // ---- phase-C weights: 2 rows of wzp/wzh per wave ----
  const int grow0 = sub * 16 + wave * 2;
  float4 Zp[2], Zh[2];
  #pragma unroll
  for (int j = 0; j < 2; ++j) {
    Zp[j] = *reinterpret_cast<const float4*>(wzp + (size_t)(grow0 + j) * HDIM + lane * 4);
    Zh[j] = *reinterpret_cast<const float4*>(wzh + (size_t)(grow0 + j) * HDIM + lane * 4);
  }
  float bzr = (lane < 2) ? bz[grow0 + lane] : 0.f;

  // ---- pin all weights into live VGPRs ----
  #pragma unroll
  for (int j = 0; j < 8; ++j)
    #pragma unroll
    for (int i = 0; i < 4; ++i) {
      PIN(WA[j][i].x); PIN(WA[j][i].y); PIN(WA[j][i].z); PIN(WA[j][i].w);
    }
  #pragma unroll
  for (int j = 0; j < 8; ++j) { PIN(Wi[j].x); PIN(Wi[j].y); }
  #pragma unroll
  for (int j = 0; j < 2; ++j)
    #pragma unroll
    for (int k = 0; k < 16; ++k) PIN(Wp[j][k]);
  #pragma unroll
  for (int j = 0; j < 2; ++j) {
    PIN(Zp[j].x); PIN(Zp[j].y); PIN(Zp[j].z); PIN(Zp[j].w);
    PIN(Zh[j].x); PIN(Zh[j].y); PIN(Zh[j].z); PIN(Zh[j].w);
  }
  PIN(wb); PIN(bzr);

  for (int s = 0; s < TSTEPS + 2; ++s) {
    const int cur = s & 1;               // LDS buffer filled during step s-1
    const int nxt = (s + 1) & 1;

    // ---- x_{s-1} from LDS (published by pollers during step s-1) ----
    float xc[16];
    const bool xc_valid = (s >= 1 && s <= TSTEPS);
    if (xc_valid) {
      #pragma unroll
      for (int k = 0; k < 16; ++k) xc[k] = lds_x[cur][k * 64 + lane];
    }

    // ---------------- phase A: x_s ----------------
    if (s < TSTEPS) {
      float acc[8];
      float2 uu = *reinterpret_cast<const float2*>(
          u + ((size_t)chain * TSTEPS + s) * IDIM + lane * 2);
      #pragma unroll
      for (int j = 0; j < 8; ++j) acc[j] = Wi[j].x * uu.x + Wi[j].y * uu.y;
      if (s > 0) {
        #pragma unroll
        for (int j = 0; j < 8; ++j) {
          float a = acc[j];
          #pragma unroll
          for (int i = 0; i < 4; ++i) {
            a += WA[j][i].x * xc[i * 4 + 0];
            a += WA[j][i].y * xc[i * 4 + 1];
            a += WA[j][i].z * xc[i * 4 + 2];
            a += WA[j][i].w * xc[i * 4 + 3];
          }
          acc[j] = a;
        }
      }
      #pragma unroll
      for (int j = 0; j < 8; ++j) acc[j] = wave_sum(acc[j]);
      float v = acc[0];
      #pragma unroll
      for (int j = 1; j < 8; ++j) v = (lane == j) ? acc[j] : v;
      if (lane < 8)
        astore64(x_buf + (((s & 1) * NCHAIN) + chain) * RDIM + rrow0 + lane,
                 pack(tanhf(v + wb), (unsigned)(s + 1)));
    }

    // ---------------- phase B: p_{s-1} (reuses xc) ----------------
    if (xc_valid) {
      const int t = s - 1;
      float a0 = 0.f, a1 = 0.f;
      #pragma unroll
      for (int k = 0; k < 16; ++k) { a0 += Wp[0][k] * xc[k]; a1 += Wp[1][k] * xc[k]; }
      a0 = wave_sum(a0);
      a1 = wave_sum(a1);
      float v = (lane == 1) ? a1 : a0;
      if (lane < 2)
        astore64(p_buf + (((t & 3) * NCHAIN) + chain) * HDIM + pcol0 + lane,
                 pack(v, (unsigned)(t + 1)));
    }

    // ---------------- phase C: h_{s-2} (LDS-fed) ----------------
    if (s >= 2) {
      const int t = s - 2;
      float pc[4], hc[4];
      #pragma unroll
      for (int k = 0; k < 4; ++k) pc[k] = lds_p[cur][k * 64 + lane];
      if (t > 0) {
        #pragma unroll
        for (int k = 0; k < 4; ++k) hc[k] = lds_h[cur][k * 64 + lane];
      } else {
        hc[0] = hc[1] = hc[2] = hc[3] = 0.f;
      }
      float a0 = Zp[0].x * pc[0] + Zp[0].y * pc[1] + Zp[0].z * pc[2] + Zp[0].w * pc[3]
               + Zh[0].x * hc[0] + Zh[0].y * hc[1] + Zh[0].z * hc[2] + Zh[0].w * hc[3];
      float a1 = Zp[1].x * pc[0] + Zp[1].y * pc[1] + Zp[1].z * pc[2] + Zp[1].w * pc[3]
               + Zh[1].x * hc[0] + Zh[1].y * hc[1] + Zh[1].z * hc[2] + Zh[1].w * hc[3];
      a0 = wave_sum(a0);
      a1 = wave_sum(a1);
      float v = (lane == 1) ? a1 : a0;
      if (lane < 2) {
        const int row = grow0 + lane;
        float z = 1.f / (1.f + expf(-(v + bzr)));
        float pt = lds_p[cur][(row & 3) * 64 + (row >> 2)];
        float hp = (t > 0) ? lds_h[cur][(row & 3) * 64 + (row >> 2)] : 0.f;
        float hnew = hp + z * (pt - hp);
        astore64(h_buf + (((t & 3) * NCHAIN) + chain) * HDIM + row,
                 pack(hnew, (unsigned)(t + 1)));
        out[((size_t)chain * TSTEPS + t) * HDIM + row] = hnew;  // fp32 output
      }
    }

    // ---- dedicated pollers: fetch step-(s+1) data, publish to LDS ----
    if (wave == 0) {
      if (s <= TSTEPS - 1) {             // x_s, tag s+1
        const u64_t* xp =
            x_buf + (((s & 1) * NCHAIN) + chain) * RDIM + lane * 16;
        const unsigned want = (unsigned)(s + 1);
        u64_t q[16];
        unsigned it = 0;
        for (;;) {
          // 16 pipelined device-scope loads, ONE waitcnt (the fix).
          asm volatile(
              "global_load_dwordx2 %[o0],  %[a], off offset:0   sc1\n\t"
              "global_load_dwordx2 %[o1],  %[a], off offset:8   sc1\n\t"
              "global_load_dwordx2 %[o2],  %[a], off offset:16  sc1\n\t"
              "global_load_dwordx2 %[o3],  %[a], off offset:24  sc1\n\t"
              "global_load_dwordx2 %[o4],  %[a], off offset:32  sc1\n\t"
              "global_load_dwordx2 %[o5],  %[a], off offset:40  sc1\n\t"
              "global_load_dwordx2 %[o6],  %[a], off offset:48  sc1\n\t"
              "global_load_dwordx2 %[o7],  %[a], off offset:56  sc1\n\t"
              "global_load_dwordx2 %[o8],  %[a], off offset:64  sc1\n\t"
              "global_load_dwordx2 %[o9],  %[a], off offset:72  sc1\n\t"
              "global_load_dwordx2 %[o10], %[a], off offset:80  sc1\n\t"
              "global_load_dwordx2 %[o11], %[a], off offset:88  sc1\n\t"
              "global_load_dwordx2 %[o12], %[a], off offset:96  sc1\n\t"
              "global_load_dwordx2 %[o13], %[a], off offset:104 sc1\n\t"
              "global_load_dwordx2 %[o14], %[a], off offset:112 sc1\n\t"
              "global_load_dwordx2 %[o15], %[a], off offset:120 sc1\n\t"
              "s_waitcnt vmcnt(0)"
              : [o0] "=&v"(q[0]), [o1] "=&v"(q[1]), [o2] "=&v"(q[2]),
                [o3] "=&v"(q[3]), [o4] "=&v"(q[4]), [o5] "=&v"(q[5]),
                [o6] "=&v"(q[6]), [o7] "=&v"(q[7]), [o8] "=&v"(q[8]),
                [o9] "=&v"(q[9]), [o10] "=&v"(q[10]), [o11] "=&v"(q[11]),
                [o12] "=&v"(q[12]), [o13] "=&v"(q[13]), [o14] "=&v"(q[14]),
                [o15] "=&v"(q[15])
              : [a] "v"(xp)
              : "memory");
          bool ok = true;
          #pragma unroll
          for (int k = 0; k < 16; ++k) ok = ok & (tag_of(q[k]) == want);
          if (ok) break;
          __builtin_amdgcn_s_sleep(1);
          if (++it > (1u << 17)) break;  // watchdog: wrong > hung
        }
        #pragma unroll
        for (int k = 0; k < 16; ++k) lds_x[nxt][k * 64 + lane] = val_of(q[k]);
      }
    } else if (wave == 1) {
      const bool needp = (s >= 1 && s <= TSTEPS);   // p_{s-1}, tag s
      const bool needh = (s >= 2 && s <= TSTEPS);   // h_{s-2}, tag s-1
      if (needp) {
        const u64_t* pvp =
            p_buf + ((((s - 1) & 3) * NCHAIN) + chain) * HDIM + lane * 4;
        const u64_t* hvp =
            h_buf + ((((s - 2) & 3) * NCHAIN) + chain) * HDIM + lane * 4;
        const unsigned wantp = (unsigned)s;
        const unsigned wanth = (unsigned)(s - 1);
        u64_t qp[4], qh[4];
        unsigned it = 0;
        for (;;) {
          // 8 pipelined loads (4 p + 4 h), ONE waitcnt. h address is a
          // valid ring slot even when !needh (tags simply not checked).
          asm volatile(
              "global_load_dwordx2 %[p0], %[pa], off offset:0  sc1\n\t"
              "global_load_dwordx2 %[p1], %[pa], off offset:8  sc1\n\t"
              "global_load_dwordx2 %[p2], %[pa], off offset:16 sc1\n\t"
              "global_load_dwordx2 %[p3], %[pa], off offset:24 sc1\n\t"
              "global_load_dwordx2 %[h0], %[ha], off offset:0  sc1\n\t"
              "global_load_dwordx2 %[h1], %[ha], off offset:8  sc1\n\t"
              "global_load_dwordx2 %[h2], %[ha], off offset:16 sc1\n\t"
              "global_load_dwordx2 %[h3], %[ha], off offset:24 sc1\n\t"
              "s_waitcnt vmcnt(0)"
              : [p0] "=&v"(qp[0]), [p1] "=&v"(qp[1]), [p2] "=&v"(qp[2]),
                [p3] "=&v"(qp[3]), [h0] "=&v"(qh[0]), [h1] "=&v"(qh[1]),
                [h2] "=&v"(qh[2]), [h3] "=&v"(qh[3])
              : [pa] "v"(pvp), [ha] "v"(hvp)
              : "memory");
          bool ok = true;
          #pragma unroll
          for (int k = 0; k < 4; ++k) ok = ok & (tag_of(qp[k]) == wantp);
          if (needh) {
            #pragma unroll
            for (int k = 0; k < 4; ++k) ok = ok & (tag_of(qh[k]) == wanth);
          }
          if (ok) break;
          __builtin_amdgcn_s_sleep(1);
          if (++it > (1u << 17)) break;
        }
        #pragma unroll
        for (int k = 0; k < 4; ++k) lds_p[nxt][k * 64 + lane] = val_of(qp[k]);
        if (needh) {
          #pragma unroll
          for (int k = 0; k < 4; ++k) lds_h[nxt][k * 64 + lane] = val_of(qh[k]);
        }
      }
    }
    __syncthreads();
  }
}

extern "C" void kernel_launch(void* const* d_in, const int* in_sizes, int n_in,
                              void* d_out, int out_size, void* d_ws, size_t ws_size,
                              hipStream_t stream) {
  // Size-based remap (defensive); positional fallback. All fp32.
  const float* ptrs[8] = {nullptr};
  const int want[8] = {TSTEPS * NCHAIN * IDIM, RDIM * IDIM, RDIM * RDIM, RDIM,
                       RDIM * HDIM, HDIM * HDIM, HDIM * HDIM, HDIM};
  if (n_in == 8) {
    int used[8] = {0};
    for (int k = 0; k < 8; ++k)
      for (int i = 0; i < n_in; ++i)
        if (!used[i] && in_sizes[i] == want[k]) {
          ptrs[k] = (const float*)d_in[i]; used[i] = 1; break;
        }
  }
  bool ok = true;
  for (int k = 0; k < 8; ++k) ok = ok && (ptrs[k] != nullptr);
  if (!ok)
    for (int k = 0; k < 8; ++k) ptrs[k] = (const float*)d_in[k];

  float* out = (float*)d_out;  // reference output dtype: float32

  // workspace: tagged u64 rings. Harness re-poisons 0xAA before every launch;
  // poison tags never match a wanted tag, so NO memset is needed.
  u64_t* x_buf = (u64_t*)d_ws;                       // 2*8*1024  (128 KB)
  u64_t* p_buf = x_buf + 2 * NCHAIN * RDIM;          // 4*8*256   (64 KB)
  u64_t* h_buf = p_buf + 4 * NCHAIN * HDIM;          // 4*8*256   (64 KB)
  size_t need_u64 = (size_t)(2 * NCHAIN * RDIM + 2 * 4 * NCHAIN * HDIM);
  if (ws_size < need_u64 * 8) return;  // zero-output diagnostic signature

  esn_fused<<<dim3(NBLOCKS), dim3(NTHR), 0, stream>>>(
      ptrs[0], ptrs[1], ptrs[2], ptrs[3], ptrs[4], ptrs[5], ptrs[6], ptrs[7],
      out, x_buf, p_buf, h_buf);
}

// Round 8
// 11364.997 us; speedup vs baseline: 6.6640x; 1.3074x over previous
//
#include <hip/hip_runtime.h>

#define TSTEPS 2048
#define NCHAIN 8
#define RDIM 1024
#define IDIM 128
#define HDIM 256
#define NB 16                    // blocks per chain
#define NTHR 512                 // 8 waves — at the 2-waves/SIMD register
                                 // cliff; R5 proved 9 waves => spill => 6x
#define NBLOCKS (NB * NCHAIN)    // 128 blocks: 1/CU, co-resident

typedef unsigned long long u64_t;

// Pin a float in a VGPR: defeat rematerialization of weight loads.
#define PIN(x) asm volatile("" : "+v"(x))

// Agent(device)-scope relaxed atomics: minimum scope for cross-block
// communication on gfx950 (per-XCD L2s not coherent; sc0 is SE-scope).
__device__ __forceinline__ u64_t aload64(const u64_t* p) {
  return __hip_atomic_load(p, __ATOMIC_RELAXED, __HIP_MEMORY_SCOPE_AGENT);
}
__device__ __forceinline__ void astore64(u64_t* p, u64_t v) {
  __hip_atomic_store(p, v, __ATOMIC_RELAXED, __HIP_MEMORY_SCOPE_AGENT);
}
// Tag-in-data: {float value (lo 32b), step tag (hi 32b)} in one atomic u64.
// Poison tag 0xAAAAAAAA never matches a wanted tag -> no memset needed.
__device__ __forceinline__ u64_t pack(float v, unsigned tag) {
  return ((u64_t)tag << 32) | (u64_t)__float_as_uint(v);
}
__device__ __forceinline__ float val_of(u64_t q) { return __uint_as_float((unsigned)q); }
__device__ __forceinline__ unsigned tag_of(u64_t q) { return (unsigned)(q >> 32); }

__device__ __forceinline__ float wave_sum(float v) {
  v += __shfl_xor(v, 1);
  v += __shfl_xor(v, 2);
  v += __shfl_xor(v, 4);
  v += __shfl_xor(v, 8);
  v += __shfl_xor(v, 16);
  v += __shfl_xor(v, 32);
  return v;
}

// R4 + ONE change: PROBE-THEN-BULK polling.
// DIAGNOSIS (R0/R4/R6/R7 all ~5.3-5.8us/step; R6 proved data-ready slots
// still cost 5.3us; R7 killed the load-serialization theory): the spin
// rounds themselves congest the MALL — 128 blocks x 2 pollers x 8-12KB per
// round ~ 3 TB/s of poll reads competing with the stores being polled.
// FIX: spin on cheap PROBES (x: 2 sentinels/lane covering both producer
// waves of the lane's strip; p/h: 4), then do ONE bulk tagged round.
// Bulk round remains fully tag-verified -> probes are a hint, never a
// correctness dependency. Poll traffic drops 4-8x.
// Everything else byte-identical to R4 (passed, 11784us).
// Ring safety: tag-checked loads complete before the barrier and before
// any later store issues; tag-chained induction certifies depth-2 x and
// depth-4 p/h rings (R1/R3/R4/R6/R7-validated).
__global__ __launch_bounds__(NTHR, 1) void esn_fused(
    const float* __restrict__ u, const float* __restrict__ w_in,
    const float* __restrict__ w, const float* __restrict__ w_bias,
    const float* __restrict__ w_pca, const float* __restrict__ wzp,
    const float* __restrict__ wzh, const float* __restrict__ bz,
    float* __restrict__ out,
    u64_t* __restrict__ x_buf,   // [2][8][1024] tagged
    u64_t* __restrict__ p_buf,   // [4][8][256] tagged
    u64_t* __restrict__ h_buf)   // [4][8][256] tagged
{
  const int bid = blockIdx.x;
  const int chain = bid & 7;           // round-robin -> same-XCD locality
  const int sub = bid >> 3;            // 0..15
  const int tid = threadIdx.x;
  const int wave = tid >> 6;           // 0..7
  const int lane = tid & 63;

  // double-buffered broadcast staging (12 KB)
  __shared__ float lds_x[2][RDIM];
  __shared__ float lds_p[2][HDIM];
  __shared__ float lds_h[2][HDIM];

  // ---- phase-A weights: 8 rows of W per wave; lane owns cols [lane*16,+16) ----
  const int rrow0 = sub * 64 + wave * 8;
  float4 WA[8][4];
  #pragma unroll
  for (int j = 0; j < 8; ++j)
    #pragma unroll
    for (int i = 0; i < 4; ++i)
      WA[j][i] = *reinterpret_cast<const float4*>(
          w + (size_t)(rrow0 + j) * RDIM + lane * 16 + i * 4);
  float2 Wi[8];
  #pragma unroll
  for (int j = 0; j < 8; ++j)
    Wi[j] = *reinterpret_cast<const float2*>(w_in + (size_t)(rrow0 + j) * IDIM + lane * 2);
  float wb = (lane < 8) ? w_bias[rrow0 + lane] : 0.f;

  // ---- phase-B weights: 2 cols of w_pca per wave ----
  const int pcol0 = sub * 16 + wave * 2;
  float Wp[2][16];
  #pragma unroll
  for (int j = 0; j < 2; ++j)
    #pragma unroll
    for (int k = 0; k < 16; ++k)
      Wp[j][k] = w_pca[(size_t)(lane * 16 + k) * HDIM + pcol0 + j];

  // ---- phase-C weights: 2 rows of wzp/wzh per wave ----
  const int grow0 = sub * 16 + wave * 2;
  float4 Zp[2], Zh[2];
  #pragma unroll
  for (int j = 0; j < 2; ++j) {
    Zp[j] = *reinterpret_cast<const float4*>(wzp + (size_t)(grow0 + j) * HDIM + lane * 4);
    Zh[j] = *reinterpret_cast<const float4*>(wzh + (size_t)(grow0 + j) * HDIM + lane * 4);
  }
  float bzr = (lane < 2) ? bz[grow0 + lane] : 0.f;

  // ---- pin all weights into live VGPRs ----
  #pragma unroll
  for (int j = 0; j < 8; ++j)
    #pragma unroll
    for (int i = 0; i < 4; ++i) {
      PIN(WA[j][i].x); PIN(WA[j][i].y); PIN(WA[j][i].z); PIN(WA[j][i].w);
    }
  #pragma unroll
  for (int j = 0; j < 8; ++j) { PIN(Wi[j].x); PIN(Wi[j].y); }
  #pragma unroll
  for (int j = 0; j < 2; ++j)
    #pragma unroll
    for (int k = 0; k < 16; ++k) PIN(Wp[j][k]);
  #pragma unroll
  for (int j = 0; j < 2; ++j) {
    PIN(Zp[j].x); PIN(Zp[j].y); PIN(Zp[j].z); PIN(Zp[j].w);
    PIN(Zh[j].x); PIN(Zh[j].y); PIN(Zh[j].z); PIN(Zh[j].w);
  }
  PIN(wb); PIN(bzr);

  for (int s = 0; s < TSTEPS + 2; ++s) {
    const int cur = s & 1;               // LDS buffer filled during step s-1
    const int nxt = (s + 1) & 1;

    // ---- x_{s-1} from LDS (published by pollers during step s-1) ----
    float xc[16];
    const bool xc_valid = (s >= 1 && s <= TSTEPS);
    if (xc_valid) {
      #pragma unroll
      for (int k = 0; k < 16; ++k) xc[k] = lds_x[cur][k * 64 + lane];
    }

    // ---------------- phase A: x_s ----------------
    if (s < TSTEPS) {
      float acc[8];
      float2 uu = *reinterpret_cast<const float2*>(
          u + ((size_t)chain * TSTEPS + s) * IDIM + lane * 2);
      #pragma unroll
      for (int j = 0; j < 8; ++j) acc[j] = Wi[j].x * uu.x + Wi[j].y * uu.y;
      if (s > 0) {
        #pragma unroll
        for (int j = 0; j < 8; ++j) {
          float a = acc[j];
          #pragma unroll
          for (int i = 0; i < 4; ++i) {
            a += WA[j][i].x * xc[i * 4 + 0];
            a += WA[j][i].y * xc[i * 4 + 1];
            a += WA[j][i].z * xc[i * 4 + 2];
            a += WA[j][i].w * xc[i * 4 + 3];
          }
          acc[j] = a;
        }
      }
      #pragma unroll
      for (int j = 0; j < 8; ++j) acc[j] = wave_sum(acc[j]);
      float v = acc[0];
      #pragma unroll
      for (int j = 1; j < 8; ++j) v = (lane == j) ? acc[j] : v;
      if (lane < 8)
        astore64(x_buf + (((s & 1) * NCHAIN) + chain) * RDIM + rrow0 + lane,
                 pack(tanhf(v + wb), (unsigned)(s + 1)));
    }

    // ---------------- phase B: p_{s-1} (reuses xc) ----------------
    if (xc_valid) {
      const int t = s - 1;
      float a0 = 0.f, a1 = 0.f;
      #pragma unroll
      for (int k = 0; k < 16; ++k) { a0 += Wp[0][k] * xc[k]; a1 += Wp[1][k] * xc[k]; }
      a0 = wave_sum(a0);
      a1 = wave_sum(a1);
      float v = (lane == 1) ? a1 : a0;
      if (lane < 2)
        astore64(p_buf + (((t & 3) * NCHAIN) + chain) * HDIM + pcol0 + lane,
                 pack(v, (unsigned)(t + 1)));
    }

    // ---------------- phase C: h_{s-2} (LDS-fed) ----------------
    if (s >= 2) {
      const int t = s - 2;
      float pc[4], hc[4];
      #pragma unroll
      for (int k = 0; k < 4; ++k) pc[k] = lds_p[cur][k * 64 + lane];
      if (t > 0) {
        #pragma unroll
        for (int k = 0; k < 4; ++k) hc[k] = lds_h[cur][k * 64 + lane];
      } else {
        hc[0] = hc[1] = hc[2] = hc[3] = 0.f;
      }
      float a0 = Zp[0].x * pc[0] + Zp[0].y * pc[1] + Zp[0].z * pc[2] + Zp[0].w * pc[3]
               + Zh[0].x * hc[0] + Zh[0].y * hc[1] + Zh[0].z * hc[2] + Zh[0].w * hc[3];
      float a1 = Zp[1].x * pc[0] + Zp[1].y * pc[1] + Zp[1].z * pc[2] + Zp[1].w * pc[3]
               + Zh[1].x * hc[0] + Zh[1].y * hc[1] + Zh[1].z * hc[2] + Zh[1].w * hc[3];
      a0 = wave_sum(a0);
      a1 = wave_sum(a1);
      float v = (lane == 1) ? a1 : a0;
      if (lane < 2) {
        const int row = grow0 + lane;
        float z = 1.f / (1.f + expf(-(v + bzr)));
        float pt = lds_p[cur][(row & 3) * 64 + (row >> 2)];
        float hp = (t > 0) ? lds_h[cur][(row & 3) * 64 + (row >> 2)] : 0.f;
        float hnew = hp + z * (pt - hp);
        astore64(h_buf + (((t & 3) * NCHAIN) + chain) * HDIM + row,
                 pack(hnew, (unsigned)(t + 1)));
        out[((size_t)chain * TSTEPS + t) * HDIM + row] = hnew;  // fp32 output
      }
    }

    // ---- dedicated pollers: probe-then-bulk fetch of step-(s+1) data ----
    if (wave == 0) {
      if (s <= TSTEPS - 1) {             // x_s, tag s+1
        const u64_t* xp =
            x_buf + (((s & 1) * NCHAIN) + chain) * RDIM + lane * 16;
        const unsigned want = (unsigned)(s + 1);
        // PROBE spin: 2 sentinels/lane (elements 7,15 — one per producer
        // wave of this lane's strip). 1KB/round vs 8KB bulk.
        unsigned it = 0;
        for (;;) {
          u64_t s0 = aload64(xp + 7);
          u64_t s1 = aload64(xp + 15);
          if ((tag_of(s0) == want) & (tag_of(s1) == want)) break;
          __builtin_amdgcn_s_sleep(1);
          if (++it > (1u << 17)) break;  // watchdog: wrong > hung
        }
        // BULK round (usually exactly one): fully tag-verified.
        u64_t q[16];
        for (;;) {
          bool ok = true;
          #pragma unroll
          for (int k = 0; k < 16; ++k) q[k] = aload64(xp + k);
          #pragma unroll
          for (int k = 0; k < 16; ++k) ok = ok & (tag_of(q[k]) == want);
          if (ok) break;
          __builtin_amdgcn_s_sleep(1);
          if (++it > (1u << 17)) break;
        }
        #pragma unroll
        for (int k = 0; k < 16; ++k) lds_x[nxt][k * 64 + lane] = val_of(q[k]);
      }
    } else if (wave == 1) {
      const bool needp = (s >= 1 && s <= TSTEPS);   // p_{s-1}, tag s
      const bool needh = (s >= 2 && s <= TSTEPS);   // h_{s-2}, tag s-1
      if (needp) {
        const u64_t* pvp =
            p_buf + ((((s - 1) & 3) * NCHAIN) + chain) * HDIM + lane * 4;
        const u64_t* hvp =
            h_buf + ((((s - 2) & 3) * NCHAIN) + chain) * HDIM + lane * 4;
        const unsigned wantp = (unsigned)s;
        const unsigned wanth = (unsigned)(s - 1);
        // PROBE spin: p[0],p[2] (+h[0],h[2]) — one per producer wave.
        unsigned it = 0;
        for (;;) {
          bool ok = (tag_of(aload64(pvp + 0)) == wantp) &
                    (tag_of(aload64(pvp + 2)) == wantp);
          if (needh)
            ok = ok & (tag_of(aload64(hvp + 0)) == wanth) &
                      (tag_of(aload64(hvp + 2)) == wanth);
          if (ok) break;
          __builtin_amdgcn_s_sleep(1);
          if (++it > (1u << 17)) break;
        }
        // BULK round: fully tag-verified.
        u64_t qp[4], qh[4];
        for (;;) {
          bool ok = true;
          #pragma unroll
          for (int k = 0; k < 4; ++k) qp[k] = aload64(pvp + k);
          if (needh) {
            #pragma unroll
            for (int k = 0; k < 4; ++k) qh[k] = aload64(hvp + k);
          }
          #pragma unroll
          for (int k = 0; k < 4; ++k) ok = ok & (tag_of(qp[k]) == wantp);
          if (needh) {
            #pragma unroll
            for (int k = 0; k < 4; ++k) ok = ok & (tag_of(qh[k]) == wanth);
          }
          if (ok) break;
          __builtin_amdgcn_s_sleep(1);
          if (++it > (1u << 17)) break;
        }
        #pragma unroll
        for (int k = 0; k < 4; ++k) lds_p[nxt][k * 64 + lane] = val_of(qp[k]);
        if (needh) {
          #pragma unroll
          for (int k = 0; k < 4; ++k) lds_h[nxt][k * 64 + lane] = val_of(qh[k]);
        }
      }
    }
    __syncthreads();
  }
}

extern "C" void kernel_launch(void* const* d_in, const int* in_sizes, int n_in,
                              void* d_out, int out_size, void* d_ws, size_t ws_size,
                              hipStream_t stream) {
  // Size-based remap (defensive); positional fallback. All fp32.
  const float* ptrs[8] = {nullptr};
  const int want[8] = {TSTEPS * NCHAIN * IDIM, RDIM * IDIM, RDIM * RDIM, RDIM,
                       RDIM * HDIM, HDIM * HDIM, HDIM * HDIM, HDIM};
  if (n_in == 8) {
    int used[8] = {0};
    for (int k = 0; k < 8; ++k)
      for (int i = 0; i < n_in; ++i)
        if (!used[i] && in_sizes[i] == want[k]) {
          ptrs[k] = (const float*)d_in[i]; used[i] = 1; break;
        }
  }
  bool ok = true;
  for (int k = 0; k < 8; ++k) ok = ok && (ptrs[k] != nullptr);
  if (!ok)
    for (int k = 0; k < 8; ++k) ptrs[k] = (const float*)d_in[k];

  float* out = (float*)d_out;  // reference output dtype: float32

  // workspace: tagged u64 rings. Harness re-poisons 0xAA before every launch;
  // poison tags never match a wanted tag, so NO memset is needed.
  u64_t* x_buf = (u64_t*)d_ws;                       // 2*8*1024  (128 KB)
  u64_t* p_buf = x_buf + 2 * NCHAIN * RDIM;          // 4*8*256   (64 KB)
  u64_t* h_buf = p_buf + 4 * NCHAIN * HDIM;          // 4*8*256   (64 KB)
  size_t need_u64 = (size_t)(2 * NCHAIN * RDIM + 2 * 4 * NCHAIN * HDIM);
  if (ws_size < need_u64 * 8) return;  // zero-output diagnostic signature

  esn_fused<<<dim3(NBLOCKS), dim3(NTHR), 0, stream>>>(
      ptrs[0], ptrs[1], ptrs[2], ptrs[3], ptrs[4], ptrs[5], ptrs[6], ptrs[7],
      out, x_buf, p_buf, h_buf);
}